// Round 1
// baseline (129.019 us; speedup 1.0000x reference)
//
#include <hip/hip_runtime.h>

typedef _Float16 f16;
typedef _Float16 f16x8 __attribute__((ext_vector_type(8)));
typedef _Float16 f16x4 __attribute__((ext_vector_type(4)));
typedef float f32x4 __attribute__((ext_vector_type(4)));

#define B_ROWS 4096
#define C_COLS 32768
#define D_DIM 256
// log2(e) / 0.05
#define LOG2E_OVER_TEMP 28.853900817779268f

#define BM 256
#define BC 64
#define CSPLIT 32
#define CPB (C_COLS / CSPLIT)  // 1024 cols per block
#define CTILES (CPB / BC)      // 16 tiles

// ---- kernel 1: fp32 -> fp16 convert (centrals), vectorized ----
__global__ void cvt_f16(const float* __restrict__ in, f16* __restrict__ out, int n8) {
  int i = blockIdx.x * blockDim.x + threadIdx.x;
  if (i >= n8) return;
  const float4* p = (const float4*)(in + (size_t)i * 8);
  float4 v0 = p[0], v1 = p[1];
  f16x8 o;
  o[0] = (f16)v0.x; o[1] = (f16)v0.y; o[2] = (f16)v0.z; o[3] = (f16)v0.w;
  o[4] = (f16)v1.x; o[5] = (f16)v1.y; o[6] = (f16)v1.z; o[7] = (f16)v1.w;
  *(f16x8*)(out + (size_t)i * 8) = o;
}

// ---- kernel 2: normalize rows of x -> fp16 (one wave per row) ----
__global__ void norm_rows(const float* __restrict__ x, f16* __restrict__ f) {
  int row = blockIdx.x * (blockDim.x >> 6) + (threadIdx.x >> 6);
  int lane = threadIdx.x & 63;
  const float4 v = *(const float4*)(x + (size_t)row * D_DIM + lane * 4);
  float ss = v.x * v.x + v.y * v.y + v.z * v.z + v.w * v.w;
  #pragma unroll
  for (int m = 1; m < 64; m <<= 1) ss += __shfl_xor(ss, m, 64);
  float inv = 1.0f / sqrtf(ss);
  f16x4 o;
  o[0] = (f16)(v.x * inv); o[1] = (f16)(v.y * inv);
  o[2] = (f16)(v.z * inv); o[3] = (f16)(v.w * inv);
  *(f16x4*)(f + (size_t)row * D_DIM + lane * 4) = o;
}

// ---- kernel 3: exact fp32 label logit -> exp (one wave per row) ----
__global__ void label_exp(const float* __restrict__ x, const float* __restrict__ cent,
                          const int* __restrict__ labels, float* __restrict__ elab) {
  int row = blockIdx.x * (blockDim.x >> 6) + (threadIdx.x >> 6);
  int lane = threadIdx.x & 63;
  int lab = labels[row];
  const float4 xv = *(const float4*)(x + (size_t)row * D_DIM + lane * 4);
  const float4 cv = *(const float4*)(cent + (size_t)lab * D_DIM + lane * 4);
  float ss = xv.x * xv.x + xv.y * xv.y + xv.z * xv.z + xv.w * xv.w;
  float dc = xv.x * cv.x + xv.y * cv.y + xv.z * cv.z + xv.w * cv.w;
  #pragma unroll
  for (int m = 1; m < 64; m <<= 1) {
    ss += __shfl_xor(ss, m, 64);
    dc += __shfl_xor(dc, m, 64);
  }
  if (lane == 0) elab[row] = exp2f(dc / sqrtf(ss) * LOG2E_OVER_TEMP);
}

// ---- kernel 4: fused f16 GEMM + exp + row-sum ----
// grid (B_ROWS/BM=16, CSPLIT=32), 512 threads (8 waves).
// A (f): 256 rows held in registers per block (each wave owns 32 rows).
// B (centrals tile): 64x256 f16 in LDS, XOR-swizzled vs 512B-stride bank conflict.
__global__ void gemm_expsum(const f16* __restrict__ f, const f16* __restrict__ cent,
                            float* __restrict__ partials) {
  __shared__ char Bs[BC * D_DIM * 2];  // 32 KB
  const int tid = threadIdx.x;
  const int w = tid >> 6, lane = tid & 63;
  const int brow0 = blockIdx.x * BM;
  const int cs = blockIdx.y;
  const int c0 = cs * CPB;
  const int fr = lane & 15, kq = lane >> 4;

  // A fragments: rows brow0 + w*32 + rf*16 + fr, k = kk*32 + kq*8 .. +8
  f16x8 a[2][8];
  {
    const f16* base = f + (size_t)(brow0 + w * 32 + fr) * D_DIM + kq * 8;
    #pragma unroll
    for (int rf = 0; rf < 2; rf++)
      #pragma unroll
      for (int kk = 0; kk < 8; kk++)
        a[rf][kk] = *(const f16x8*)(base + rf * 16 * D_DIM + kk * 32);
  }

  float s[2][4] = {{0.f, 0.f, 0.f, 0.f}, {0.f, 0.f, 0.f, 0.f}};
  const f32x4 vzero = {0.f, 0.f, 0.f, 0.f};

  for (int t = 0; t < CTILES; t++) {
    const int ct0 = c0 + t * BC;
    __syncthreads();
    // stage B tile: 64 rows x 256 k f16 = 2048 x 16B chunks, 4 per thread
    #pragma unroll
    for (int i = 0; i < 4; i++) {
      int chunk = tid + i * 512;
      int c = chunk >> 5, kc = chunk & 31;
      f16x8 v = *(const f16x8*)(cent + (size_t)(ct0 + c) * D_DIM + kc * 8);
      int off = (c * 512 + kc * 16) ^ ((c & 7) << 4);
      *(f16x8*)(Bs + off) = v;
    }
    __syncthreads();

    f32x4 acc[2][4];
    #pragma unroll
    for (int rf = 0; rf < 2; rf++)
      #pragma unroll
      for (int cf = 0; cf < 4; cf++)
        acc[rf][cf] = vzero;

    #pragma unroll
    for (int kk = 0; kk < 8; kk++) {
      f16x8 bf[4];
      #pragma unroll
      for (int cf = 0; cf < 4; cf++) {
        int c = cf * 16 + fr;
        int off = (c * 512 + kk * 64 + kq * 16) ^ ((c & 7) << 4);
        bf[cf] = *(const f16x8*)(Bs + off);
      }
      #pragma unroll
      for (int rf = 0; rf < 2; rf++)
        #pragma unroll
        for (int cf = 0; cf < 4; cf++)
          acc[rf][cf] = __builtin_amdgcn_mfma_f32_16x16x32_f16(a[rf][kk], bf[cf], acc[rf][cf], 0, 0, 0);
    }

    // exp + accumulate row partial sums (lane holds col fr per frag, rows kq*4+r)
    #pragma unroll
    for (int rf = 0; rf < 2; rf++)
      #pragma unroll
      for (int cf = 0; cf < 4; cf++)
        #pragma unroll
        for (int r = 0; r < 4; r++)
          s[rf][r] += __builtin_amdgcn_exp2f(acc[rf][cf][r] * LOG2E_OVER_TEMP);
  }

  // reduce across the 16 lanes of each row-group (cols), then write partials
  #pragma unroll
  for (int rf = 0; rf < 2; rf++)
    #pragma unroll
    for (int r = 0; r < 4; r++) {
      float v = s[rf][r];
      v += __shfl_xor(v, 1, 64);
      v += __shfl_xor(v, 2, 64);
      v += __shfl_xor(v, 4, 64);
      v += __shfl_xor(v, 8, 64);
      s[rf][r] = v;
    }
  if (fr == 0) {
    int rowbase = brow0 + w * 32;
    #pragma unroll
    for (int rf = 0; rf < 2; rf++)
      #pragma unroll
      for (int r = 0; r < 4; r++)
        partials[(size_t)cs * B_ROWS + rowbase + rf * 16 + kq * 4 + r] = s[rf][r];
  }
}

// ---- kernel 5: combine ----
__global__ void finalize(const float* __restrict__ partials, const float* __restrict__ elab,
                         float* __restrict__ out) {
  int b = blockIdx.x * blockDim.x + threadIdx.x;
  if (b >= B_ROWS) return;
  float ssum = 0.f;
  #pragma unroll
  for (int cs = 0; cs < CSPLIT; cs++) ssum += partials[(size_t)cs * B_ROWS + b];
  out[b] = elab[b] / ssum;
}

extern "C" void kernel_launch(void* const* d_in, const int* in_sizes, int n_in,
                              void* d_out, int out_size, void* d_ws, size_t ws_size,
                              hipStream_t stream) {
  const float* x = (const float*)d_in[0];
  const float* cent = (const float*)d_in[1];
  const int* labels = (const int*)d_in[2];
  float* out = (float*)d_out;

  char* ws = (char*)d_ws;
  f16* f16f = (f16*)ws;                                   // 4096*256*2   = 2 MB
  f16* f16c = (f16*)(ws + (size_t)B_ROWS * D_DIM * 2);    // 32768*256*2  = 16 MB
  float* partials = (float*)(ws + (size_t)B_ROWS * D_DIM * 2 + (size_t)C_COLS * D_DIM * 2);
  float* elab = partials + (size_t)CSPLIT * B_ROWS;       // + 512 KB

  int n8 = C_COLS * D_DIM / 8;  // 1,048,576
  cvt_f16<<<n8 / 256, 256, 0, stream>>>(cent, f16c, n8);
  norm_rows<<<B_ROWS / 4, 256, 0, stream>>>(x, f16f);
  label_exp<<<B_ROWS / 4, 256, 0, stream>>>(x, cent, labels, elab);
  gemm_expsum<<<dim3(B_ROWS / BM, CSPLIT), 512, 0, stream>>>(f16f, f16c, partials);
  finalize<<<B_ROWS / 256, 256, 0, stream>>>(partials, elab, out);
}

// Round 2
// 84.646 us; speedup vs baseline: 1.5242x; 1.5242x over previous
//
#include <hip/hip_runtime.h>
#include <stdint.h>

typedef _Float16 f16;
typedef _Float16 f16x8 __attribute__((ext_vector_type(8)));
typedef _Float16 f16x4 __attribute__((ext_vector_type(4)));
typedef float f32x4 __attribute__((ext_vector_type(4)));

#define B_ROWS 4096
#define C_COLS 32768
#define D_DIM 256
// log2(e) / 0.05
#define LOG2E_OVER_TEMP 28.853900817779268f

#define BM 256                  // rows per block (4 waves x 64 rows)
#define BC 64                   // cols per LDS tile
#define CSPLIT 32
#define CPB (C_COLS / CSPLIT)   // 1024 cols per block
#define CTILES (CPB / BC)       // 16 tiles
#define NWAVES 4

typedef __attribute__((address_space(3))) char lds_char_t;
typedef __attribute__((address_space(1))) const char glb_char_t;

// ---- kernel 1: fp32 -> fp16 convert (centrals), vectorized ----
__global__ void cvt_f16(const float* __restrict__ in, f16* __restrict__ out, int n8) {
  int i = blockIdx.x * blockDim.x + threadIdx.x;
  if (i >= n8) return;
  const float4* p = (const float4*)(in + (size_t)i * 8);
  float4 v0 = p[0], v1 = p[1];
  f16x8 o;
  o[0] = (f16)v0.x; o[1] = (f16)v0.y; o[2] = (f16)v0.z; o[3] = (f16)v0.w;
  o[4] = (f16)v1.x; o[5] = (f16)v1.y; o[6] = (f16)v1.z; o[7] = (f16)v1.w;
  *(f16x8*)(out + (size_t)i * 8) = o;
}

// ---- kernel 2: fused row-normalize -> f16  AND  exact fp32 label logit -> exp ----
// one wave per row
__global__ void prep_rows(const float* __restrict__ x, const float* __restrict__ cent,
                          const int* __restrict__ labels, f16* __restrict__ f,
                          float* __restrict__ elab) {
  int row = blockIdx.x * (blockDim.x >> 6) + (threadIdx.x >> 6);
  int lane = threadIdx.x & 63;
  int lab = labels[row];
  const float4 xv = *(const float4*)(x + (size_t)row * D_DIM + lane * 4);
  const float4 cv = *(const float4*)(cent + (size_t)lab * D_DIM + lane * 4);
  float ss = xv.x * xv.x + xv.y * xv.y + xv.z * xv.z + xv.w * xv.w;
  float dc = xv.x * cv.x + xv.y * cv.y + xv.z * cv.z + xv.w * cv.w;
  #pragma unroll
  for (int m = 1; m < 64; m <<= 1) {
    ss += __shfl_xor(ss, m, 64);
    dc += __shfl_xor(dc, m, 64);
  }
  float inv = 1.0f / sqrtf(ss);
  f16x4 o;
  o[0] = (f16)(xv.x * inv); o[1] = (f16)(xv.y * inv);
  o[2] = (f16)(xv.z * inv); o[3] = (f16)(xv.w * inv);
  *(f16x4*)(f + (size_t)row * D_DIM + lane * 4) = o;
  if (lane == 0) elab[row] = exp2f(dc * inv * LOG2E_OVER_TEMP);
}

// ---- staging: async global->LDS, 16B/lane, pre-swizzled global source ----
// LDS layout target: chunk (c, kc) at byte (c*512 + kc*16) ^ ((c&7)<<4).
// global_load_lds writes linearly (uniform base + lane*16), so lane reading
// slot s fetches the chunk that belongs there: c = s>>5, kc = (s&31)^(c&7).
__device__ __forceinline__ void stage_tile(const f16* __restrict__ src, char* buf,
                                           int w, int lane) {
  #pragma unroll
  for (int i = 0; i < 8; i++) {
    int slot_hi = i * NWAVES + w;          // wave-uniform
    int s = slot_hi * 64 + lane;
    int c = s >> 5;
    int kc = (s & 31) ^ (c & 7);
    const f16* g = src + c * D_DIM + kc * 8;
    __builtin_amdgcn_global_load_lds((glb_char_t*)(const void*)g,
                                     (lds_char_t*)(void*)(buf + slot_hi * 1024),
                                     16, 0, 0);
  }
}

// ---- kernel 3: fused f16 GEMM + exp + row-sum ----
// 512 blocks x 256 threads (4 waves). Each wave owns 64 rows in registers.
// B tile (64 x 256 f16 = 32KB) double-buffered in LDS, async-prefetched.
__global__ void __launch_bounds__(256, 2)
gemm_expsum(const f16* __restrict__ f, const f16* __restrict__ cent,
            float* __restrict__ partials) {
  __shared__ char Bs[2][BC * D_DIM * 2];   // 2 x 32 KB
  const int tid = threadIdx.x;
  const int w = tid >> 6, lane = tid & 63;
  const int fr = lane & 15, kq = lane >> 4;

  // XCD-aware decode: xcd = bid&7 owns cs in [xcd*4, xcd*4+4) -> B-slice L2-local
  const int bid = blockIdx.x;
  const int xcd = bid & 7;
  const int j = bid >> 3;                  // 0..63
  const int bx = j & 15;                   // row-block
  const int cs = xcd * 4 + (j >> 4);       // col-split 0..31
  const int brow0 = bx * BM;
  const int c0 = cs * CPB;

  // A fragments: rows brow0 + w*64 + rf*16 + fr, k = kk*32 + kq*8 .. +8
  f16x8 a[4][8];
  {
    const f16* base = f + (size_t)(brow0 + w * 64 + fr) * D_DIM + kq * 8;
    #pragma unroll
    for (int rf = 0; rf < 4; rf++)
      #pragma unroll
      for (int kk = 0; kk < 8; kk++)
        a[rf][kk] = *(const f16x8*)(base + rf * 16 * D_DIM + kk * 32);
  }

  float s[4][4] = {{0.f,0.f,0.f,0.f},{0.f,0.f,0.f,0.f},{0.f,0.f,0.f,0.f},{0.f,0.f,0.f,0.f}};
  const f32x4 vzero = {0.f, 0.f, 0.f, 0.f};

  stage_tile(cent + (size_t)c0 * D_DIM, Bs[0], w, lane);

  for (int t = 0; t < CTILES; t++) {
    __syncthreads();   // implicit vmcnt(0): stage(t) landed; readers of buf[(t+1)&1] done
    if (t + 1 < CTILES)
      stage_tile(cent + (size_t)(c0 + (t + 1) * BC) * D_DIM, Bs[(t + 1) & 1], w, lane);

    const char* buf = Bs[t & 1];
    #pragma unroll
    for (int cf = 0; cf < 4; cf++) {
      f32x4 acc[4] = {vzero, vzero, vzero, vzero};
      #pragma unroll
      for (int kk = 0; kk < 8; kk++) {
        const int c = cf * 16 + fr;
        const int off = (c * 512 + kk * 64 + kq * 16) ^ ((c & 7) << 4);
        f16x8 bf = *(const f16x8*)(buf + off);
        #pragma unroll
        for (int rf = 0; rf < 4; rf++)
          acc[rf] = __builtin_amdgcn_mfma_f32_16x16x32_f16(a[rf][kk], bf, acc[rf], 0, 0, 0);
      }
      // exp + accumulate row partial sums (lane holds col fr, rows kq*4+r)
      #pragma unroll
      for (int rf = 0; rf < 4; rf++)
        #pragma unroll
        for (int r = 0; r < 4; r++)
          s[rf][r] += __builtin_amdgcn_exp2f(acc[rf][r] * LOG2E_OVER_TEMP);
    }
  }

  // reduce across the 16 lanes (cols) of each row-group, then write partials
  #pragma unroll
  for (int rf = 0; rf < 4; rf++)
    #pragma unroll
    for (int r = 0; r < 4; r++) {
      float v = s[rf][r];
      v += __shfl_xor(v, 1, 64);
      v += __shfl_xor(v, 2, 64);
      v += __shfl_xor(v, 4, 64);
      v += __shfl_xor(v, 8, 64);
      s[rf][r] = v;
    }
  if (fr == 0) {
    int rowbase = brow0 + w * 64;
    #pragma unroll
    for (int rf = 0; rf < 4; rf++)
      #pragma unroll
      for (int r = 0; r < 4; r++)
        partials[(size_t)cs * B_ROWS + rowbase + rf * 16 + kq * 4 + r] = s[rf][r];
  }
}

// ---- kernel 4: combine ----
__global__ void finalize(const float* __restrict__ partials, const float* __restrict__ elab,
                         float* __restrict__ out) {
  int b = blockIdx.x * blockDim.x + threadIdx.x;
  if (b >= B_ROWS) return;
  float ssum = 0.f;
  #pragma unroll
  for (int cs = 0; cs < CSPLIT; cs++) ssum += partials[(size_t)cs * B_ROWS + b];
  out[b] = elab[b] / ssum;
}

extern "C" void kernel_launch(void* const* d_in, const int* in_sizes, int n_in,
                              void* d_out, int out_size, void* d_ws, size_t ws_size,
                              hipStream_t stream) {
  const float* x = (const float*)d_in[0];
  const float* cent = (const float*)d_in[1];
  const int* labels = (const int*)d_in[2];
  float* out = (float*)d_out;

  char* ws = (char*)d_ws;
  f16* f16f = (f16*)ws;                                   // 4096*256*2   = 2 MB
  f16* f16c = (f16*)(ws + (size_t)B_ROWS * D_DIM * 2);    // 32768*256*2  = 16 MB
  float* partials = (float*)(ws + (size_t)B_ROWS * D_DIM * 2 + (size_t)C_COLS * D_DIM * 2);
  float* elab = partials + (size_t)CSPLIT * B_ROWS;       // + 512 KB

  int n8 = C_COLS * D_DIM / 8;  // 1,048,576
  cvt_f16<<<n8 / 256, 256, 0, stream>>>(cent, f16c, n8);
  prep_rows<<<B_ROWS / 4, 256, 0, stream>>>(x, cent, labels, f16f, elab);
  gemm_expsum<<<dim3(B_ROWS / BM * CSPLIT), 256, 0, stream>>>(f16f, f16c, partials);
  finalize<<<B_ROWS / 256, 256, 0, stream>>>(partials, elab, out);
}